// Round 2
// baseline (10167.075 us; speedup 1.0000x reference)
//
#include <hip/hip_runtime.h>

// Problem constants
// B=16, CIN=512, COUT=512, K=3, SDIM=512, H=W=64
static constexpr float SCALE_C   = 0.014731391274719742f;  // 1/sqrt(512*9)
static constexpr float LIN_SCALE = 0.04419417382415922f;   // 1/sqrt(512)
static constexpr float EPS_C     = 1e-8f;

// ---------------- kernel 1: modulated style scalars sm[b][i] ----------------
// sm[b][i] = (LIN_SCALE * dot(style[b], mod_weight[i]) + mod_bias[i]) * pmask[b][i]
__global__ void k_style(const float* __restrict__ style, const float* __restrict__ prob,
                        const float* __restrict__ mod_weight, const float* __restrict__ mod_bias,
                        float* __restrict__ sm) {
    int b = blockIdx.x;
    __shared__ float st[512];
    for (int k = threadIdx.x; k < 512; k += 256) st[k] = style[b * 512 + k];
    __syncthreads();
    // thresh = floor(round(prob*8)/8 * 512 * 0.5) = rint(prob*8)*32 (exact)
    float thresh = rintf(prob[b] * 8.0f) * 32.0f;
    for (int i = threadIdx.x; i < 512; i += 256) {
        const float4* mw = (const float4*)(mod_weight + (size_t)i * 512);
        float acc = 0.f;
#pragma unroll 4
        for (int k = 0; k < 128; ++k) {
            float4 w4 = mw[k];
            acc += w4.x * st[4 * k] + w4.y * st[4 * k + 1] + w4.z * st[4 * k + 2] + w4.w * st[4 * k + 3];
        }
        float s = acc * LIN_SCALE + mod_bias[i];
        sm[b * 512 + i] = ((float)i >= thresh) ? s : 0.f;
    }
}

// ---------------- kernel 2: wsq[o][i] = sum_{3x3} weight^2 ----------------
__global__ void k_wsq(const float* __restrict__ weight, float* __restrict__ wsq) {
    int idx = blockIdx.x * 256 + threadIdx.x;  // 0..262143 == o*512+i
    const float* wp = weight + (size_t)idx * 9;
    float s = 0.f;
#pragma unroll
    for (int k = 0; k < 9; ++k) s += wp[k] * wp[k];
    wsq[idx] = s;
}

// ---------------- kernel 3: rnorm[o] = 1/max(||weight_row_o||, 1e-12) ----------------
__global__ void k_norm(const float* __restrict__ wsq, float* __restrict__ rnorm) {
    int o = blockIdx.x;
    int lane = threadIdx.x;
    float s = 0.f;
    for (int i = lane; i < 512; i += 64) s += wsq[o * 512 + i];
#pragma unroll
    for (int off = 32; off > 0; off >>= 1) s += __shfl_down(s, off);
    if (lane == 0) rnorm[o] = 1.0f / fmaxf(sqrtf(s), 1e-12f);
}

// ---------------- kernel 4: cscale[b][o] = SCALE * demod[b][o] ----------------
__global__ void k_demod(const float* __restrict__ sm, const float* __restrict__ wsq,
                        float* __restrict__ cscale) {
    int wid = threadIdx.x >> 6, lane = threadIdx.x & 63;
    int gid = blockIdx.x * 4 + wid;  // b*512 + o
    int b = gid >> 9, o = gid & 511;
    float s = 0.f;
    for (int i = lane; i < 512; i += 64) {
        float v = sm[b * 512 + i];
        s += v * v * wsq[o * 512 + i];
    }
#pragma unroll
    for (int off = 32; off > 0; off >>= 1) s += __shfl_down(s, off);
    if (lane == 0) cscale[gid] = SCALE_C / sqrtf(SCALE_C * SCALE_C * s + EPS_C);
}

// ---------------- kernel 5: the conv (implicit GEMM, f32 vector FMA) ----------------
// Block: 256 threads. Tile: 128 couts x 128 pixels (2 rows of 64). IC=8 channel chunk.
// Thread (px = tid&15, og = tid>>4): 8 couts (og*8..+7) x 8 pixels (px + 16*(m&3), row m>>2).
#define WPAD 132  // 72 rows of [ic*9+kh*3+kw][cout], padded: multiple of 4 for b128, %32=4 for banks
__global__ __launch_bounds__(256) void k_conv(
    const float* __restrict__ input, const float* __restrict__ weight,
    const float* __restrict__ sm, const float* __restrict__ cscale,
    float* __restrict__ out) {
    __shared__ float Wl[72 * WPAD];   // 38.0 KB
    __shared__ float Xl[8][4][68];    // 8.7 KB, col c == input x (c-1)
    const int b  = blockIdx.z;
    const int o0 = blockIdx.y * 128;
    const int y0 = blockIdx.x * 2;
    const int tid = threadIdx.x;
    const int px = tid & 15;
    const int og = tid >> 4;

    float acc[8][8];
#pragma unroll
    for (int i = 0; i < 8; ++i)
#pragma unroll
        for (int j = 0; j < 8; ++j) acc[i][j] = 0.f;

    const float* smb = sm + b * 512;

#pragma unroll 1
    for (int ic0 = 0; ic0 < 512; ic0 += 8) {
        __syncthreads();
        // stage W tile: 72 x 128, global coalesced along r (runs of 72 floats per cout)
#pragma unroll
        for (int j = 0; j < 36; ++j) {
            int f = tid + j * 256;       // 0..9215
            int o = f / 72;
            int r = f - o * 72;          // r = ic*9 + kh*3 + kw
            Wl[r * WPAD + o] = weight[(size_t)(o0 + o) * 4608 + ic0 * 9 + r];
        }
        // stage X tile: 8 ch x 4 rows x 66 cols, modulation folded in
#pragma unroll
        for (int j = 0; j < 9; ++j) {
            int f = tid + j * 256;
            if (f < 2112) {
                int c = f % 66;
                int t2 = f / 66;
                int row = t2 & 3;
                int ch = t2 >> 2;
                int gy = y0 - 1 + row;
                int gx = c - 1;
                float v = 0.f;
                if ((unsigned)gy < 64u && (unsigned)gx < 64u)
                    v = input[(((size_t)b * 512 + ic0 + ch) * 64 + gy) * 64 + gx] * smb[ic0 + ch];
                Xl[ch][row][c] = v;
            }
        }
        __syncthreads();
        // compute: 72 steps x 64 FMA/thread
#pragma unroll 1
        for (int ic = 0; ic < 8; ++ic) {
#pragma unroll
            for (int kh = 0; kh < 3; ++kh) {
#pragma unroll
                for (int kw = 0; kw < 3; ++kw) {
                    int r = ic * 9 + kh * 3 + kw;
                    const float4 wa = *(const float4*)&Wl[r * WPAD + og * 8];
                    const float4 wb = *(const float4*)&Wl[r * WPAD + og * 8 + 4];
                    float wv[8] = {wa.x, wa.y, wa.z, wa.w, wb.x, wb.y, wb.z, wb.w};
                    float xs[8];
#pragma unroll
                    for (int m = 0; m < 8; ++m)
                        xs[m] = Xl[ic][(m >> 2) + kh][px + ((m & 3) << 4) + kw];
#pragma unroll
                    for (int oj = 0; oj < 8; ++oj)
#pragma unroll
                        for (int m = 0; m < 8; ++m)
                            acc[oj][m] = fmaf(wv[oj], xs[m], acc[oj][m]);
                }
            }
        }
    }
    // epilogue: scale by SCALE*demod and store
#pragma unroll
    for (int oj = 0; oj < 8; ++oj) {
        int o = o0 + og * 8 + oj;
        float cs = cscale[b * 512 + o];
#pragma unroll
        for (int m = 0; m < 8; ++m) {
            int row = y0 + (m >> 2);
            int col = px + ((m & 3) << 4);
            out[(((size_t)b * 512 + o) * 64 + row) * 64 + col] = acc[oj][m] * cs;
        }
    }
}

// ---------------- kernel 6: co = normalized weight gram matrix ----------------
// 64x64 tile per block, 256 threads, 4x4 per thread, K chunked by 32.
__global__ void k_co(const float* __restrict__ weight, const float* __restrict__ rnorm,
                     float* __restrict__ co) {
    __shared__ float Al[32][68];
    __shared__ float Bl[32][68];
    int bi = blockIdx.y, bj = blockIdx.x;
    int tid = threadIdx.x;
    int tx = tid & 15, ty = tid >> 4;
    float acc[4][4] = {};
#pragma unroll 1
    for (int k0 = 0; k0 < 4608; k0 += 32) {
        __syncthreads();
#pragma unroll
        for (int j = 0; j < 8; ++j) {
            int f = tid + j * 256;   // 0..2047
            int o = f >> 5, k = f & 31;
            Al[k][o] = weight[(size_t)(bi * 64 + o) * 4608 + k0 + k];
            Bl[k][o] = weight[(size_t)(bj * 64 + o) * 4608 + k0 + k];
        }
        __syncthreads();
#pragma unroll
        for (int kk = 0; kk < 32; ++kk) {
            float4 a = *(const float4*)&Al[kk][ty * 4];
            float4 bv4 = *(const float4*)&Bl[kk][tx * 4];
            float av[4] = {a.x, a.y, a.z, a.w};
            float bv[4] = {bv4.x, bv4.y, bv4.z, bv4.w};
#pragma unroll
            for (int ii = 0; ii < 4; ++ii)
#pragma unroll
                for (int jj = 0; jj < 4; ++jj)
                    acc[ii][jj] = fmaf(av[ii], bv[jj], acc[ii][jj]);
        }
    }
#pragma unroll
    for (int ii = 0; ii < 4; ++ii) {
        int o1 = bi * 64 + ty * 4 + ii;
        float r1 = rnorm[o1];
        float4 v;
        float* vp = &v.x;
#pragma unroll
        for (int jj = 0; jj < 4; ++jj) {
            int o2 = bj * 64 + tx * 4 + jj;
            vp[jj] = acc[ii][jj] * r1 * rnorm[o2];
        }
        *(float4*)&co[(size_t)o1 * 512 + bj * 64 + tx * 4] = v;
    }
}

extern "C" void kernel_launch(void* const* d_in, const int* in_sizes, int n_in,
                              void* d_out, int out_size, void* d_ws, size_t ws_size,
                              hipStream_t stream) {
    const float* input      = (const float*)d_in[0];  // (16,512,64,64)
    const float* prob       = (const float*)d_in[1];  // (16,)
    const float* style      = (const float*)d_in[2];  // (16,512)
    const float* weight     = (const float*)d_in[3];  // (1,512,512,3,3)
    const float* mod_weight = (const float*)d_in[4];  // (512,512)
    const float* mod_bias   = (const float*)d_in[5];  // (512,)

    float* out = (float*)d_out;                 // (16,512,64,64) flat
    float* co  = out + (size_t)16 * 512 * 64 * 64;  // (512,512)

    float* ws     = (float*)d_ws;
    float* sm     = ws;                 // 16*512
    float* wsq    = ws + 8192;          // 512*512
    float* rnorm  = ws + 270336;        // 512
    float* cscale = ws + 270848;        // 16*512

    k_style<<<16, 256, 0, stream>>>(style, prob, mod_weight, mod_bias, sm);
    k_wsq<<<1024, 256, 0, stream>>>(weight, wsq);
    k_norm<<<512, 64, 0, stream>>>(wsq, rnorm);
    k_demod<<<2048, 256, 0, stream>>>(sm, wsq, cscale);
    k_conv<<<dim3(32, 4, 16), 256, 0, stream>>>(input, weight, sm, cscale, out);
    k_co<<<dim3(8, 8), 256, 0, stream>>>(weight, rnorm, co);
}

// Round 3
// 2635.325 us; speedup vs baseline: 3.8580x; 3.8580x over previous
//
#include <hip/hip_runtime.h>

// Problem constants: B=16, CIN=512, COUT=512, K=3, SDIM=512, H=W=64
static constexpr float SCALE_C   = 0.014731391274719742f;  // 1/sqrt(512*9)
static constexpr float LIN_SCALE = 0.04419417382415922f;   // 1/sqrt(512)
static constexpr float EPS_C     = 1e-8f;

typedef __attribute__((ext_vector_type(8))) short bf16x8;
typedef __attribute__((ext_vector_type(4))) float f32x4;

__device__ __forceinline__ unsigned bf16_rne(float v) {
    unsigned u = __float_as_uint(v);
    return (u + 0x7FFFu + ((u >> 16) & 1u)) >> 16;
}

// ---------------- kernel 1: modulated style scalars sm[b][i] ----------------
__global__ void k_style(const float* __restrict__ style, const float* __restrict__ prob,
                        const float* __restrict__ mod_weight, const float* __restrict__ mod_bias,
                        float* __restrict__ sm) {
    int b = blockIdx.x;
    __shared__ float st[512];
    for (int k = threadIdx.x; k < 512; k += 256) st[k] = style[b * 512 + k];
    __syncthreads();
    float thresh = rintf(prob[b] * 8.0f) * 32.0f;  // floor(round(p*8)/8*256) exact
    for (int i = threadIdx.x; i < 512; i += 256) {
        const float4* mw = (const float4*)(mod_weight + (size_t)i * 512);
        float acc = 0.f;
#pragma unroll 4
        for (int k = 0; k < 128; ++k) {
            float4 w4 = mw[k];
            acc += w4.x * st[4 * k] + w4.y * st[4 * k + 1] + w4.z * st[4 * k + 2] + w4.w * st[4 * k + 3];
        }
        float s = acc * LIN_SCALE + mod_bias[i];
        sm[b * 512 + i] = ((float)i >= thresh) ? s : 0.f;
    }
}

// ---------------- kernel 2: wsq[o][i] = sum_{3x3} weight^2 ----------------
__global__ void k_wsq(const float* __restrict__ weight, float* __restrict__ wsq) {
    int idx = blockIdx.x * 256 + threadIdx.x;  // o*512+i
    const float* wp = weight + (size_t)idx * 9;
    float s = 0.f;
#pragma unroll
    for (int k = 0; k < 9; ++k) s += wp[k] * wp[k];
    wsq[idx] = s;
}

// ---------------- kernel 3: rnorm[o] = 1/max(||w_o||,1e-12) ----------------
__global__ void k_norm(const float* __restrict__ wsq, float* __restrict__ rnorm) {
    int o = blockIdx.x;
    int lane = threadIdx.x;
    float s = 0.f;
    for (int i = lane; i < 512; i += 64) s += wsq[o * 512 + i];
#pragma unroll
    for (int off = 32; off > 0; off >>= 1) s += __shfl_down(s, off);
    if (lane == 0) rnorm[o] = 1.0f / fmaxf(sqrtf(s), 1e-12f);
}

// ---------------- kernel 4: cscale[b][o] = SCALE * demod[b][o] ----------------
__global__ void k_demod(const float* __restrict__ sm, const float* __restrict__ wsq,
                        float* __restrict__ cscale) {
    int wid = threadIdx.x >> 6, lane = threadIdx.x & 63;
    int gid = blockIdx.x * 4 + wid;  // b*512 + o
    int b = gid >> 9, o = gid & 511;
    float s = 0.f;
    for (int i = lane; i < 512; i += 64) {
        float v = sm[b * 512 + i];
        s += v * v * wsq[o * 512 + i];
    }
#pragma unroll
    for (int off = 32; off > 0; off >>= 1) s += __shfl_down(s, off);
    if (lane == 0) cscale[gid] = SCALE_C / sqrtf(SCALE_C * SCALE_C * s + EPS_C);
}

// ---------------- kernel 4.5: split weight into bf16 hi/lo, layout [r][o][i] ----------------
__global__ void k_wsplit(const float* __restrict__ weight,
                         unsigned short* __restrict__ whi, unsigned short* __restrict__ wlo) {
    int idx = blockIdx.x * 256 + threadIdx.x;  // o*512 + i
    int o = idx >> 9, i = idx & 511;
    const float* wp = weight + (size_t)idx * 9;
#pragma unroll
    for (int r = 0; r < 9; ++r) {
        float v = wp[r];
        unsigned hi = bf16_rne(v);
        float hf = __uint_as_float(hi << 16);
        unsigned lo = bf16_rne(v - hf);
        size_t a = ((size_t)(r * 512 + o)) * 512 + i;
        whi[a] = (unsigned short)hi;
        wlo[a] = (unsigned short)lo;
    }
}

// ---------------- kernel 5: conv via split-bf16 MFMA (bf16x3) ----------------
// Block 256 thr = 4 waves. Block tile: 256 pixels (16y x 16x) x 128 couts.
// Wave w: 64 px (y rows w*4..w*4+3) x 128 co; frags a=4 (m) x b=8 (n).
// K = input channels, chunk 32 (one MFMA K). 9 taps shift the LDS pixel row.
// LDS rows padded to 40 ch (80B) -> 2-way bank conflicts only.
__global__ __launch_bounds__(256, 2) void k_conv_mfma(
    const float* __restrict__ input, const unsigned short* __restrict__ whi,
    const unsigned short* __restrict__ wlo, const float* __restrict__ sm,
    const float* __restrict__ cscale, float* __restrict__ out) {
    __shared__ __attribute__((aligned(16))) unsigned short lds[36160];
    unsigned short* Xh = lds;            // [324 pix][40 ch]
    unsigned short* Xl = lds + 12960;
    unsigned short* Wh = lds + 25920;    // [128 co][40 ch]
    unsigned short* Wl = lds + 31040;

    const int tid = threadIdx.x;
    const int lane = tid & 63;
    const int w = tid >> 6;
    const int b = blockIdx.z;
    const int co0 = blockIdx.y * 128;
    const int y0 = (blockIdx.x >> 2) * 16;
    const int x0 = (blockIdx.x & 3) * 16;

    const int l15 = lane & 15;
    const int l4 = lane >> 4;
    const int ABlane = l15 * 40 + l4 * 8;  // element offset into padded row-major [row][40]

    f32x4 acc[4][8];
#pragma unroll
    for (int i = 0; i < 4; ++i)
#pragma unroll
        for (int j = 0; j < 8; ++j) acc[i][j] = (f32x4){0.f, 0.f, 0.f, 0.f};

    const float* smb = sm + b * 512;

#pragma unroll 1
    for (int ic0 = 0; ic0 < 512; ic0 += 32) {
        __syncthreads();
        // ---- stage X: 18x18 halo x 32 ch, fold sm, split hi/lo ----
#pragma unroll
        for (int j = 0; j < 41; ++j) {
            int f = tid + j * 256;
            if (f < 10368) {
                int ch = f / 324;
                int rem = f - ch * 324;
                int py = rem / 18;
                int pxc = rem - py * 18;
                int gy = y0 - 1 + py;
                int gx = x0 - 1 + pxc;
                float v = 0.f;
                if ((unsigned)gy < 64u && (unsigned)gx < 64u)
                    v = input[(((size_t)b * 512 + ic0 + ch) * 64 + gy) * 64 + gx] * smb[ic0 + ch];
                unsigned hi = bf16_rne(v);
                float hf = __uint_as_float(hi << 16);
                unsigned lo = bf16_rne(v - hf);
                int a = (py * 18 + pxc) * 40 + ch;
                Xh[a] = (unsigned short)hi;
                Xl[a] = (unsigned short)lo;
            }
        }
        // ---- 9 taps ----
#pragma unroll
        for (int kh = 0; kh < 3; ++kh)
#pragma unroll
            for (int kw = 0; kw < 3; ++kw) {
                const int r = kh * 3 + kw;
                if (r) __syncthreads();  // protect Wh/Wl vs previous tap's reads
                // stage W[r]: [128 co][32 ch] hi+lo (bf16 pre-split, L2-hot)
#pragma unroll
                for (int j = 0; j < 2; ++j) {
                    int f = tid + j * 256;        // 0..511
                    int ol = f >> 2, icq = f & 3;
                    size_t ga = ((size_t)(r * 512 + co0 + ol)) * 512 + ic0 + icq * 8;
                    *(bf16x8*)&Wh[ol * 40 + icq * 8] = *(const bf16x8*)&whi[ga];
                    *(bf16x8*)&Wl[ol * 40 + icq * 8] = *(const bf16x8*)&wlo[ga];
                }
                __syncthreads();
                // fragments + MFMA
                bf16x8 Ah[4], Al[4];
#pragma unroll
                for (int mg = 0; mg < 4; ++mg) {
                    int a = ((w * 4 + mg + kh) * 18 + kw) * 40 + ABlane;
                    Ah[mg] = *(const bf16x8*)&Xh[a];
                    Al[mg] = *(const bf16x8*)&Xl[a];
                }
#pragma unroll
                for (int ng = 0; ng < 8; ++ng) {
                    int bo = ng * 640 + ABlane;   // ng*16 rows * 40
                    bf16x8 Bh = *(const bf16x8*)&Wh[bo];
                    bf16x8 Bl = *(const bf16x8*)&Wl[bo];
#pragma unroll
                    for (int mg = 0; mg < 4; ++mg) {
                        acc[mg][ng] = __builtin_amdgcn_mfma_f32_16x16x32_bf16(Ah[mg], Bh, acc[mg][ng], 0, 0, 0);
                        acc[mg][ng] = __builtin_amdgcn_mfma_f32_16x16x32_bf16(Al[mg], Bh, acc[mg][ng], 0, 0, 0);
                        acc[mg][ng] = __builtin_amdgcn_mfma_f32_16x16x32_bf16(Ah[mg], Bl, acc[mg][ng], 0, 0, 0);
                    }
                }
            }
    }
    // ---- epilogue: scale by SCALE*demod, store f32x4 (4 consecutive x) ----
#pragma unroll
    for (int ng = 0; ng < 8; ++ng) {
        int o = co0 + ng * 16 + l15;
        float cs = cscale[b * 512 + o];
#pragma unroll
        for (int mg = 0; mg < 4; ++mg) {
            int y = y0 + w * 4 + mg;
            f32x4 v = acc[mg][ng];
            v[0] *= cs; v[1] *= cs; v[2] *= cs; v[3] *= cs;
            *(f32x4*)&out[(((size_t)b * 512 + o) * 64 + y) * 64 + x0 + l4 * 4] = v;
        }
    }
}

// ---------------- kernel 5 (fallback): f32 vector conv ----------------
#define WPAD 132
__global__ __launch_bounds__(256) void k_conv_f32(
    const float* __restrict__ input, const float* __restrict__ weight,
    const float* __restrict__ sm, const float* __restrict__ cscale,
    float* __restrict__ out) {
    __shared__ float Wlds[72 * WPAD];
    __shared__ float Xlds[8][4][68];
    const int b = blockIdx.z;
    const int o0 = blockIdx.y * 128;
    const int y0 = blockIdx.x * 2;
    const int tid = threadIdx.x;
    const int px = tid & 15;
    const int og = tid >> 4;
    float acc[8][8];
#pragma unroll
    for (int i = 0; i < 8; ++i)
#pragma unroll
        for (int j = 0; j < 8; ++j) acc[i][j] = 0.f;
    const float* smb = sm + b * 512;
#pragma unroll 1
    for (int ic0 = 0; ic0 < 512; ic0 += 8) {
        __syncthreads();
#pragma unroll
        for (int j = 0; j < 36; ++j) {
            int f = tid + j * 256;
            int o = f / 72;
            int r = f - o * 72;
            Wlds[r * WPAD + o] = weight[(size_t)(o0 + o) * 4608 + ic0 * 9 + r];
        }
#pragma unroll
        for (int j = 0; j < 9; ++j) {
            int f = tid + j * 256;
            if (f < 2112) {
                int c = f % 66;
                int t2 = f / 66;
                int row = t2 & 3;
                int ch = t2 >> 2;
                int gy = y0 - 1 + row;
                int gx = c - 1;
                float v = 0.f;
                if ((unsigned)gy < 64u && (unsigned)gx < 64u)
                    v = input[(((size_t)b * 512 + ic0 + ch) * 64 + gy) * 64 + gx] * smb[ic0 + ch];
                Xlds[ch][row][c] = v;
            }
        }
        __syncthreads();
#pragma unroll 1
        for (int ic = 0; ic < 8; ++ic) {
#pragma unroll
            for (int kh = 0; kh < 3; ++kh) {
#pragma unroll
                for (int kw = 0; kw < 3; ++kw) {
                    int r = ic * 9 + kh * 3 + kw;
                    const float4 wa = *(const float4*)&Wlds[r * WPAD + og * 8];
                    const float4 wb = *(const float4*)&Wlds[r * WPAD + og * 8 + 4];
                    float wv[8] = {wa.x, wa.y, wa.z, wa.w, wb.x, wb.y, wb.z, wb.w};
                    float xs[8];
#pragma unroll
                    for (int m = 0; m < 8; ++m)
                        xs[m] = Xlds[ic][(m >> 2) + kh][px + ((m & 3) << 4) + kw];
#pragma unroll
                    for (int oj = 0; oj < 8; ++oj)
#pragma unroll
                        for (int m = 0; m < 8; ++m)
                            acc[oj][m] = fmaf(wv[oj], xs[m], acc[oj][m]);
                }
            }
        }
    }
#pragma unroll
    for (int oj = 0; oj < 8; ++oj) {
        int o = o0 + og * 8 + oj;
        float cs = cscale[b * 512 + o];
#pragma unroll
        for (int m = 0; m < 8; ++m) {
            int row = y0 + (m >> 2);
            int col = px + ((m & 3) << 4);
            out[(((size_t)b * 512 + o) * 64 + row) * 64 + col] = acc[oj][m] * cs;
        }
    }
}

// ---------------- kernel 6: co = normalized weight gram matrix ----------------
__global__ void k_co(const float* __restrict__ weight, const float* __restrict__ rnorm,
                     float* __restrict__ co) {
    __shared__ float Al[32][68];
    __shared__ float Bl[32][68];
    int bi = blockIdx.y, bj = blockIdx.x;
    int tid = threadIdx.x;
    int tx = tid & 15, ty = tid >> 4;
    float acc[4][4] = {};
#pragma unroll 1
    for (int k0 = 0; k0 < 4608; k0 += 32) {
        __syncthreads();
#pragma unroll
        for (int j = 0; j < 8; ++j) {
            int f = tid + j * 256;
            int o = f >> 5, k = f & 31;
            Al[k][o] = weight[(size_t)(bi * 64 + o) * 4608 + k0 + k];
            Bl[k][o] = weight[(size_t)(bj * 64 + o) * 4608 + k0 + k];
        }
        __syncthreads();
#pragma unroll
        for (int kk = 0; kk < 32; ++kk) {
            float4 a = *(const float4*)&Al[kk][ty * 4];
            float4 bv4 = *(const float4*)&Bl[kk][tx * 4];
            float av[4] = {a.x, a.y, a.z, a.w};
            float bv[4] = {bv4.x, bv4.y, bv4.z, bv4.w};
#pragma unroll
            for (int ii = 0; ii < 4; ++ii)
#pragma unroll
                for (int jj = 0; jj < 4; ++jj)
                    acc[ii][jj] = fmaf(av[ii], bv[jj], acc[ii][jj]);
        }
    }
#pragma unroll
    for (int ii = 0; ii < 4; ++ii) {
        int o1 = bi * 64 + ty * 4 + ii;
        float r1 = rnorm[o1];
        float4 v;
        float* vp = &v.x;
#pragma unroll
        for (int jj = 0; jj < 4; ++jj) {
            int o2 = bj * 64 + tx * 4 + jj;
            vp[jj] = acc[ii][jj] * r1 * rnorm[o2];
        }
        *(float4*)&co[(size_t)o1 * 512 + bj * 64 + tx * 4] = v;
    }
}

extern "C" void kernel_launch(void* const* d_in, const int* in_sizes, int n_in,
                              void* d_out, int out_size, void* d_ws, size_t ws_size,
                              hipStream_t stream) {
    const float* input      = (const float*)d_in[0];
    const float* prob       = (const float*)d_in[1];
    const float* style      = (const float*)d_in[2];
    const float* weight     = (const float*)d_in[3];
    const float* mod_weight = (const float*)d_in[4];
    const float* mod_bias   = (const float*)d_in[5];

    float* out = (float*)d_out;
    float* co  = out + (size_t)16 * 512 * 64 * 64;

    float* ws     = (float*)d_ws;
    float* sm     = ws;                 // 16*512
    float* wsq    = ws + 8192;          // 512*512
    float* rnorm  = ws + 270336;        // 512
    float* cscale = ws + 270848;        // 16*512 -> ends at float 279040
    unsigned short* whi = (unsigned short*)(ws + 279040);  // 9*512*512 bf16
    unsigned short* wlo = whi + (size_t)9 * 512 * 512;

    const size_t ws_need = (size_t)279040 * 4 + 2ull * 9 * 512 * 512 * 2;  // ~10.6 MB
    const bool use_mfma = ws_size >= ws_need;

    k_style<<<16, 256, 0, stream>>>(style, prob, mod_weight, mod_bias, sm);
    k_wsq<<<1024, 256, 0, stream>>>(weight, wsq);
    k_norm<<<512, 64, 0, stream>>>(wsq, rnorm);
    k_demod<<<2048, 256, 0, stream>>>(sm, wsq, cscale);
    if (use_mfma) {
        k_wsplit<<<1024, 256, 0, stream>>>(weight, whi, wlo);
        k_conv_mfma<<<dim3(16, 4, 16), 256, 0, stream>>>(input, whi, wlo, sm, cscale, out);
    } else {
        k_conv_f32<<<dim3(32, 4, 16), 256, 0, stream>>>(input, weight, sm, cscale, out);
    }
    k_co<<<dim3(8, 8), 256, 0, stream>>>(weight, rnorm, co);
}